// Round 3
// baseline (2015.217 us; speedup 1.0000x reference)
//
#include <hip/hip_runtime.h>

#define B_ 4
#define C_ 384
#define H_ 224
#define W_ 224
#define HH_ 28
#define WW_ 28
#define NS_ 784   // superpixels per image (28*28)

// ---------- bf16 helpers (LDS compaction only; global I/O is fp32) ----------
__device__ __forceinline__ float bf2f(unsigned int u) {
    union { unsigned int i; float f; } v; v.i = u << 16; return v.f;
}
__device__ __forceinline__ unsigned int f2bf(float f) {
    union { float f; unsigned int i; } v; v.f = f;
    unsigned int x = v.i;
    return (x + 0x7FFFu + ((x >> 16) & 1u)) >> 16;
}

// ---------- K1: 8x8 mean pool: xs(B,C,H,W) fp32 -> sf(B,C,28,28) fp32 ----------
__global__ __launch_bounds__(256) void k_pool(const float* __restrict__ xs,
                                              float* __restrict__ sf) {
    int idx = blockIdx.x * 256 + threadIdx.x;
    if (idx >= B_ * C_ * HH_ * WW_) return;
    int j  = idx % WW_;
    int t1 = idx / WW_;
    int i  = t1 % HH_;
    int t2 = t1 / HH_;
    int c  = t2 % C_;
    int b  = t2 / C_;
    const float* p = xs + (((long)(b * C_ + c)) * H_ + i * 8) * (long)W_ + j * 8;
    float s = 0.f;
#pragma unroll
    for (int r = 0; r < 8; ++r) {
        float4 v0 = *(const float4*)(p + (long)r * W_);
        float4 v1 = *(const float4*)(p + (long)r * W_ + 4);
        s += v0.x + v0.y + v0.z + v0.w + v1.x + v1.y + v1.z + v1.w;
    }
    sf[idx] = s * (1.f / 64.f);
}

// ---------- K2: affinity softmax + super-token aggregation (fold via atomics) ----------
// one block per (b, superpixel n)
__global__ __launch_bounds__(256) void k_aff(const float* __restrict__ xs,
                                             const float* __restrict__ sf,
                                             float* __restrict__ affG,
                                             float* __restrict__ sft,
                                             float* __restrict__ asum) {
    __shared__ unsigned short pixT[C_ * 66];   // [c][p] bf16, stride 66 (50,688 B)
    __shared__ float smem2[C_ * 9];            // phase1: sf9[c][k]; later affL[p][k] (13,824 B)

    int t  = threadIdx.x;
    int wg = blockIdx.x;
    int b  = wg / NS_, n = wg % NS_;
    int sa = n / WW_, sb = n % WW_;

    // stage pixels: pixT[c][r*8+s] = bf16(xs[b,c,8sa+r,8sb+s])
    for (int e = t; e < C_ * 8; e += 256) {
        int c = e >> 3, r = e & 7;
        const float* g = xs + (((long)(b * C_ + c)) * H_ + sa * 8 + r) * (long)W_ + sb * 8;
        float4 v0 = *(const float4*)g;
        float4 v1 = *(const float4*)(g + 4);
        unsigned int* dst = (unsigned int*)&pixT[c * 66 + r * 8];
        dst[0] = f2bf(v0.x) | (f2bf(v0.y) << 16);
        dst[1] = f2bf(v0.z) | (f2bf(v0.w) << 16);
        dst[2] = f2bf(v1.x) | (f2bf(v1.y) << 16);
        dst[3] = f2bf(v1.z) | (f2bf(v1.w) << 16);
    }
    // stage sf9[c][k] (zero-padded out of range -> logit contribution 0, matching reference)
    for (int e = t; e < C_ * 9; e += 256) {
        int c = e / 9, k = e - c * 9;
        int y = sa + k / 3 - 1, x = sb + (k % 3) - 1;
        float v = 0.f;
        if ((unsigned)y < HH_ && (unsigned)x < WW_)
            v = sf[(((long)(b * C_ + c)) * HH_ + y) * WW_ + x];
        smem2[e] = v;
    }
    __syncthreads();

    // phase 1: logits. wave w handles pixels w*16..w*16+15; lane = cg*16+pl, cg = channel quarter
    int w = t >> 6, lane = t & 63;
    int cg = lane >> 4, pl = lane & 15;
    int p = w * 16 + pl;
    float lg[9];
#pragma unroll
    for (int k = 0; k < 9; ++k) lg[k] = 0.f;
    for (int cc = 0; cc < 96; ++cc) {
        int c = cg * 96 + cc;
        float a = bf2f(pixT[c * 66 + p]);
#pragma unroll
        for (int k = 0; k < 9; ++k) lg[k] += a * smem2[c * 9 + k];
    }
#pragma unroll
    for (int k = 0; k < 9; ++k) {
        lg[k] += __shfl_xor(lg[k], 16);
        lg[k] += __shfl_xor(lg[k], 32);
    }
    __syncthreads();   // sf9 reads done; smem2 now reusable as affL

    if (cg == 0) {
        const float SCALE = 0.05103103630798288f;   // 384^-0.5
        float m = -1e30f;
#pragma unroll
        for (int k = 0; k < 9; ++k) { lg[k] *= SCALE; m = fmaxf(m, lg[k]); }
        float s = 0.f;
#pragma unroll
        for (int k = 0; k < 9; ++k) { lg[k] = __expf(lg[k] - m); s += lg[k]; }
        float inv = 1.f / s;
        float* ag = affG + (((long)(b * NS_ + n)) * 64 + p) * 9;
#pragma unroll
        for (int k = 0; k < 9; ++k) {
            float a = lg[k] * inv;
            smem2[p * 9 + k] = a;   // affL[p][k]
            ag[k] = a;
        }
    }
    __syncthreads();

    // aff_sum fold (scatter-add): threads 0..8 each handle one tap
    if (t < 9) {
        float s = 0.f;
        for (int pp = 0; pp < 64; ++pp) s += smem2[pp * 9 + t];
        int y = sa + t / 3 - 1, x = sb + (t % 3) - 1;
        if ((unsigned)y < HH_ && (unsigned)x < WW_)
            atomicAdd(&asum[(b * HH_ + y) * WW_ + x], s);
    }

    // phase 3: sft_local[c][k] = sum_p pix[p][c]*aff[p][k], scatter-add fold
    for (int c = t; c < C_; c += 256) {
        float acc[9];
#pragma unroll
        for (int k = 0; k < 9; ++k) acc[k] = 0.f;
        for (int pp = 0; pp < 64; ++pp) {
            float a = bf2f(pixT[c * 66 + pp]);
#pragma unroll
            for (int k = 0; k < 9; ++k) acc[k] += a * smem2[pp * 9 + k];
        }
#pragma unroll
        for (int k = 0; k < 9; ++k) {
            int y = sa + k / 3 - 1, x = sb + (k % 3) - 1;
            if ((unsigned)y < HH_ && (unsigned)x < WW_)
                atomicAdd(&sft[(((long)(b * C_ + c)) * HH_ + y) * WW_ + x], acc[k]);
        }
    }
}

// ---------- K3: sft /= (aff_sum + 1e-12) ----------
__global__ __launch_bounds__(256) void k_norm(float* __restrict__ sft,
                                              const float* __restrict__ asum) {
    int idx = blockIdx.x * 256 + threadIdx.x;
    if (idx >= B_ * C_ * NS_) return;
    int hw = idx % NS_;
    int b  = idx / (C_ * NS_);
    sft[idx] = sft[idx] / (asum[b * NS_ + hw] + 1e-12f);
}

// ---------- K4: GEMM  out[b,m,n] (or out[b,n,m] if trans) = sum_k W[m,k]*X[b,k,n] (+bias) ----------
// W fp32 (M,384), X fp32 (b,384,784). grid = b*(M/64)*13, block 256, 64x64 tile, 4x4/thread.
__global__ __launch_bounds__(256) void k_gemm(const float* __restrict__ Wg,
                                              const float* __restrict__ X,
                                              float* __restrict__ out,
                                              const float* __restrict__ bias,
                                              int M, int trans) {
    int nt = blockIdx.x % 13;
    int rest = blockIdx.x / 13;
    int Mt = M >> 6;
    int mt = rest % Mt, b = rest / Mt;
    int m0 = mt * 64, n0 = nt * 64;

    __shared__ float wL[16][64];
    __shared__ float xL[16][64];

    int t = threadIdx.x;
    int mi = t >> 4, ni = t & 15;
    float acc[4][4];
#pragma unroll
    for (int a = 0; a < 4; ++a)
#pragma unroll
        for (int c = 0; c < 4; ++c) acc[a][c] = 0.f;

    int wm = t >> 2, wk = (t & 3) * 4;

    for (int k0 = 0; k0 < 384; k0 += 16) {
        __syncthreads();
        {   // stage W tile, transposed into wL[k][m]
            const float* wp = Wg + (long)(m0 + wm) * 384 + k0 + wk;
            float4 v = *(const float4*)wp;
            wL[wk + 0][wm] = v.x;
            wL[wk + 1][wm] = v.y;
            wL[wk + 2][wm] = v.z;
            wL[wk + 3][wm] = v.w;
        }
#pragma unroll
        for (int i2 = 0; i2 < 4; ++i2) {   // stage X tile
            int e = t + i2 * 256;
            int kk = e >> 6, nn = e & 63;
            int n = n0 + nn;
            xL[kk][nn] = (n < NS_) ? X[((long)b * C_ + k0 + kk) * NS_ + n] : 0.f;
        }
        __syncthreads();
#pragma unroll
        for (int kk = 0; kk < 16; ++kk) {
            float wv[4], xv[4];
#pragma unroll
            for (int im = 0; im < 4; ++im) wv[im] = wL[kk][mi * 4 + im];
#pragma unroll
            for (int in = 0; in < 4; ++in) xv[in] = xL[kk][ni * 4 + in];
#pragma unroll
            for (int im = 0; im < 4; ++im)
#pragma unroll
                for (int in = 0; in < 4; ++in) acc[im][in] += wv[im] * xv[in];
        }
    }

#pragma unroll
    for (int im = 0; im < 4; ++im) {
        int m = m0 + mi * 4 + im;
        float bv = bias ? bias[m] : 0.f;
        if (!trans) {
            int n = n0 + ni * 4;
            if (n < NS_) {
                float4 v = make_float4(acc[im][0] + bv, acc[im][1] + bv,
                                       acc[im][2] + bv, acc[im][3] + bv);
                *(float4*)&out[((long)b * M + m) * NS_ + n] = v;
            }
        } else {
#pragma unroll
            for (int in = 0; in < 4; ++in) {
                int n = n0 + ni * 4 + in;
                if (n < NS_) out[((long)b * NS_ + n) * C_ + m] = acc[im][in] + bv;
            }
        }
    }
}

// ---------- K5: attention. grid = b*8*49, block 256. 16 queries per block. ----------
__global__ __launch_bounds__(256) void k_attn(const float* __restrict__ qkv,
                                              float* __restrict__ attno) {
    __shared__ float scL[16 * 785];    // scores [q][n], stride 785
    __shared__ float qL[48][16];
    __shared__ float kvT[48][32];
    __shared__ float red[16][17];
    __shared__ float mrow[16];
    __shared__ float linv[16];

    int t = threadIdx.x;
    int wgid = blockIdx.x;
    int qc = wgid % 49;
    int h  = (wgid / 49) & 7;
    int b  = wgid / (49 * 8);
    int q0 = qc * 16;
    const float* base = qkv + ((long)(b * 1152 + h * 144)) * NS_;

    for (int e = t; e < 768; e += 256) {   // stage Q
        int d = e >> 4, q = e & 15;
        qL[d][q] = base[(long)d * NS_ + q0 + q];
    }

    // pass 1: scores
    for (int kt0 = 0; kt0 < NS_; kt0 += 32) {
        __syncthreads();
        int kw = NS_ - kt0; if (kw > 32) kw = 32;
        for (int e = t; e < 48 * 32; e += 256) {
            int d = e >> 5, kk = e & 31;
            kvT[d][kk] = (kk < kw) ? base[(long)(48 + d) * NS_ + kt0 + kk] : 0.f;
        }
        __syncthreads();
#pragma unroll
        for (int it = 0; it < 2; ++it) {
            int item = t + it * 256;
            int q = item & 15, kk = item >> 4;
            if (kt0 + kk < NS_) {
                float a = 0.f;
#pragma unroll
                for (int d = 0; d < 48; ++d) a += qL[d][q] * kvT[d][kk];
                scL[q * 785 + kt0 + kk] = a * 0.14433756729740643f;   // 48^-0.5
            }
        }
    }
    __syncthreads();

    // softmax over keys (rows of scL)
    int q = t & 15, seg = t >> 4;
    {
        float m = -1e30f;
        for (int i = 0; i < 49; ++i) m = fmaxf(m, scL[q * 785 + seg * 49 + i]);
        red[q][seg] = m;
    }
    __syncthreads();
    if (t < 16) {
        float m = red[t][0];
        for (int i = 1; i < 16; ++i) m = fmaxf(m, red[t][i]);
        mrow[t] = m;
    }
    __syncthreads();
    {
        float mq = mrow[q];
        float s = 0.f;
        for (int i = 0; i < 49; ++i) {
            float e = __expf(scL[q * 785 + seg * 49 + i] - mq);
            scL[q * 785 + seg * 49 + i] = e;
            s += e;
        }
        red[q][seg] = s;
    }
    __syncthreads();
    if (t < 16) {
        float s = 0.f;
        for (int i = 0; i < 16; ++i) s += red[t][i];
        linv[t] = 1.f / s;
    }
    __syncthreads();

    // pass 2: PV
    float li = linv[q];
    int db = t >> 4;
    float acc0 = 0.f, acc1 = 0.f, acc2 = 0.f;
    for (int kt0 = 0; kt0 < NS_; kt0 += 32) {
        __syncthreads();
        int kw = NS_ - kt0; if (kw > 32) kw = 32;
        for (int e = t; e < 48 * 32; e += 256) {
            int d = e >> 5, kk = e & 31;
            kvT[d][kk] = (kk < kw) ? base[(long)(96 + d) * NS_ + kt0 + kk] : 0.f;
        }
        __syncthreads();
        for (int kk = 0; kk < kw; ++kk) {
            float p2 = scL[q * 785 + kt0 + kk];
            acc0 += p2 * kvT[db][kk];
            acc1 += p2 * kvT[db + 16][kk];
            acc2 += p2 * kvT[db + 32][kk];
        }
    }
    long ob = ((long)(b * C_ + h * 48)) * NS_ + q0 + q;
    attno[ob + (long)db * NS_]        = acc0 * li;
    attno[ob + (long)(db + 16) * NS_] = acc1 * li;
    attno[ob + (long)(db + 32) * NS_] = acc2 * li;
}

// ---------- K6: scatter refined super-tokens back to pixels; fp32 output ----------
// one block per (b, n). projo layout [b][n][c] (n-major, from trans GEMM).
__global__ __launch_bounds__(256) void k_scatter(const float* __restrict__ projo,
                                                 const float* __restrict__ affG,
                                                 float* __restrict__ out) {
    __shared__ float nbL[9][C_];
    __shared__ float affL[64 * 9];
    int t = threadIdx.x;
    int wg = blockIdx.x;
    int b  = wg / NS_, n = wg % NS_;
    int sa = n / WW_, sb = n % WW_;

    for (int e = t; e < 9 * C_; e += 256) {
        int k = e / C_, c = e - k * C_;
        int y = sa + k / 3 - 1, x = sb + (k % 3) - 1;
        nbL[k][c] = ((unsigned)y < HH_ && (unsigned)x < WW_)
                        ? projo[((long)(b * NS_ + y * WW_ + x)) * C_ + c] : 0.f;
    }
    for (int e = t; e < 576; e += 256)
        affL[e] = affG[((long)(b * NS_ + n)) * 576 + e];
    __syncthreads();

    int r = t & 7, cb = t >> 3;
    float ar[8][9];
#pragma unroll
    for (int s2 = 0; s2 < 8; ++s2)
#pragma unroll
        for (int k = 0; k < 9; ++k) ar[s2][k] = affL[(r * 8 + s2) * 9 + k];

    for (int cc = 0; cc < 12; ++cc) {
        int c = cb + cc * 32;
        float nb[9];
#pragma unroll
        for (int k = 0; k < 9; ++k) nb[k] = nbL[k][c];
        float ov[8];
#pragma unroll
        for (int s2 = 0; s2 < 8; ++s2) {
            float o = 0.f;
#pragma unroll
            for (int k = 0; k < 9; ++k) o += nb[k] * ar[s2][k];
            ov[s2] = o;
        }
        long ob = (((long)(b * C_ + c)) * H_ + sa * 8 + r) * (long)W_ + sb * 8;
        *(float4*)&out[ob]     = make_float4(ov[0], ov[1], ov[2], ov[3]);
        *(float4*)&out[ob + 4] = make_float4(ov[4], ov[5], ov[6], ov[7]);
    }
}

// ---------- scratch layout ----------
// d_ws (fp32 elems): only what the FINAL kernel needs (12.04 MB total)
#define WS_AFF   0L
#define WS_PROJ  1806336L
// d_out used as bulk fp32 scratch (77M floats available; all regions below are
// dead before k_scatter overwrites d_out with the final fp32 result)
#define DO_SF    0L
#define DO_SFT   1204224L
#define DO_ASUM  2408448L
#define DO_QKV   2411584L
#define DO_ATTN  6024256L

extern "C" void kernel_launch(void* const* d_in, const int* in_sizes, int n_in,
                              void* d_out, int out_size, void* d_ws, size_t ws_size,
                              hipStream_t stream) {
    const float* xs     = (const float*)d_in[0];
    const float* qkv_w  = (const float*)d_in[2];
    const float* proj_w = (const float*)d_in[3];
    const float* proj_b = (const float*)d_in[4];
    float* out = (float*)d_out;
    float* ws  = (float*)d_ws;
    float* osc = (float*)d_out;   // d_out as bulk scratch (308 MB >> 29 MB used)

    float* affG  = ws + WS_AFF;
    float* projo = ws + WS_PROJ;
    float* sf    = osc + DO_SF;
    float* sft   = osc + DO_SFT;
    float* asum  = osc + DO_ASUM;
    float* qkvb  = osc + DO_QKV;
    float* attno = osc + DO_ATTN;

    // zero the fold (scatter-add) targets: sft + asum are contiguous
    hipMemsetAsync(sft, 0, (1204224L + 3136L) * sizeof(float), stream);

    k_pool<<<4704, 256, 0, stream>>>(xs, sf);
    k_aff<<<B_ * NS_, 256, 0, stream>>>(xs, sf, affG, sft, asum);
    k_norm<<<4704, 256, 0, stream>>>(sft, asum);
    k_gemm<<<4 * 18 * 13, 256, 0, stream>>>(qkv_w, sft, qkvb, nullptr, 1152, 0);
    k_attn<<<4 * 8 * 49, 256, 0, stream>>>(qkvb, attno);
    k_gemm<<<4 * 6 * 13, 256, 0, stream>>>(proj_w, attno, projo, proj_b, 384, 1);
    k_scatter<<<B_ * NS_, 256, 0, stream>>>(projo, affG, out);
}